// Round 3
// baseline (548.346 us; speedup 1.0000x reference)
//
#include <hip/hip_runtime.h>
#include <math.h>

#define Bn 32
#define Pn 42840
#define On 64
#define NIn 8
#define Cn 11
#define ATT_N (32*56*96)
#define THRESHOLD_F 0.4f
#define THETA_F 0.1f

// IoU of two corner-format boxes, mirroring the jnp op order exactly.
__device__ __forceinline__ float iou_c(float ax1,float ay1,float ax2,float ay2,
                                       float bx1,float by1,float bx2,float by2){
  float ltx=fmaxf(ax1,bx1), lty=fmaxf(ay1,by1);
  float rbx=fminf(ax2,bx2), rby=fminf(ay2,by2);
  float w=fmaxf(rbx-ltx,0.0f), h=fmaxf(rby-lty,0.0f);
  float inter=w*h;
  float aa=(ax2-ax1)*(ay2-ay1);
  float ab=(bx2-bx1)*(by2-by1);
  return inter/((aa+ab)-inter);
}

// ---- seg loss: sum of max(log1p(-a), -100); negated at the end ----
__global__ void seg_kernel(const float* __restrict__ att, double* __restrict__ acc){
  int i = blockIdx.x*256 + threadIdx.x;
  float v = 0.0f;
  if (i < ATT_N) v = fmaxf(log1pf(-att[i]), -100.0f);
  __shared__ float s[256];
  int t = threadIdx.x;
  s[t]=v; __syncthreads();
  for (int st=128; st>0; st>>=1){ if (t<st) s[t]+=s[t+st]; __syncthreads(); }
  if (t==0) atomicAdd(&acc[0], (double)s[0]);
}

// ---- phase A: per (b,p): max/argmax over objects (first occurrence), ignored flag ----
__global__ void phaseA_kernel(const float* __restrict__ boxes,
                              const float* __restrict__ ign,
                              const float* __restrict__ priors,
                              float* __restrict__ ov_prior,
                              int* __restrict__ objinfo){
  __shared__ float sb[On*4];
  __shared__ float si[NIn*4];
  int b = blockIdx.y;
  int t = threadIdx.x;
  if (t < On*4)  sb[t] = boxes[(size_t)b*On*4 + t];
  if (t < NIn*4) si[t] = ign[(size_t)b*NIn*4 + t];
  __syncthreads();
  int p = blockIdx.x*256 + t;
  if (p >= Pn) return;
  float4 pc = ((const float4*)priors)[p];
  float px1 = pc.x - pc.z/2.0f, py1 = pc.y - pc.w/2.0f;
  float px2 = pc.x + pc.z/2.0f, py2 = pc.y + pc.w/2.0f;
  float best = -1.0f; int besto = 0;
  #pragma unroll 4
  for (int o=0;o<On;o++){
    float v = iou_c(sb[4*o],sb[4*o+1],sb[4*o+2],sb[4*o+3], px1,py1,px2,py2);
    if (v > best){ best = v; besto = o; }   // strict > keeps first argmax
  }
  float ig = iou_c(si[0],si[1],si[2],si[3], px1,py1,px2,py2);
  #pragma unroll
  for (int o=1;o<NIn;o++)
    ig = fmaxf(ig, iou_c(si[4*o],si[4*o+1],si[4*o+2],si[4*o+3], px1,py1,px2,py2));
  size_t bp = (size_t)b*Pn + p;
  ov_prior[bp] = best;
  objinfo[bp]  = besto | ((ig >= THETA_F) ? 256 : 0);
}

// ---- phase B: per (b,o): max/argmax over P (first occurrence via packed key) ----
__global__ void phaseB_kernel(const float* __restrict__ boxes,
                              const float* __restrict__ priors,
                              float* __restrict__ ov_obj,
                              int* __restrict__ prior_obj){
  int b = blockIdx.y, o = blockIdx.x, t = threadIdx.x;
  const float* bx = boxes + ((size_t)b*On + o)*4;
  float ax1=bx[0], ay1=bx[1], ax2=bx[2], ay2=bx[3];
  unsigned long long key = 0ull;   // loses to any real key (low32=~p > 0)
  for (int p=t; p<Pn; p+=256){
    float4 pc = ((const float4*)priors)[p];
    float px1 = pc.x - pc.z/2.0f, py1 = pc.y - pc.w/2.0f;
    float px2 = pc.x + pc.z/2.0f, py2 = pc.y + pc.w/2.0f;
    float v = iou_c(ax1,ay1,ax2,ay2, px1,py1,px2,py2);  // v >= 0 -> bits ordered
    unsigned long long k = ((unsigned long long)__float_as_uint(v) << 32)
                         | (unsigned long long)(0xFFFFFFFFu - (unsigned)p);
    if (k > key) key = k;
  }
  __shared__ unsigned long long sk[256];
  sk[t] = key; __syncthreads();
  for (int st=128; st>0; st>>=1){
    if (t<st && sk[t+st] > sk[t]) sk[t] = sk[t+st];
    __syncthreads();
  }
  if (t==0){
    ov_obj[(size_t)b*On+o]   = __uint_as_float((unsigned)(sk[0] >> 32));
    prior_obj[(size_t)b*On+o]= (int)(0xFFFFFFFFu - (unsigned)(sk[0] & 0xFFFFFFFFu));
  }
}

// ---- phase C: sequential per-batch scatter (set 1.0; last-write-wins rank) ----
__global__ void phaseC_kernel(const float* __restrict__ ov_obj,
                              const int* __restrict__ prior_obj,
                              float* __restrict__ ov_prior,
                              int* __restrict__ objinfo){
  int b = threadIdx.x;
  if (b >= Bn) return;
  int rank = -1;
  for (int o=0;o<On;o++){
    if (ov_obj[(size_t)b*On+o] > 0.0f){
      rank++;                                   // jranks = cumsum(valid)-1
      int p = prior_obj[(size_t)b*On+o];
      size_t bp = (size_t)b*Pn + p;
      ov_prior[bp] = 1.0f;
      objinfo[bp] = (objinfo[bp] & 256) | rank; // ascending o => overwrite == max(jr)
    }
  }
}

// ---- phase D: labels, CE, DIoU over positives, conf_neg array, partial sums ----
__global__ void phaseD_kernel(const float* __restrict__ odm_locs,
                              const float* __restrict__ odm_scores,
                              const float* __restrict__ boxes,
                              const int* __restrict__ labels,
                              const float* __restrict__ priors,
                              const float* __restrict__ ov_prior,
                              const int* __restrict__ objinfo,
                              float* __restrict__ conf_neg,
                              int* __restrict__ n_pos,
                              double* __restrict__ acc){
  int b = blockIdx.y;
  int p = blockIdx.x*256 + threadIdx.x;
  float locv = 0.0f, confpv = 0.0f; int posv = 0;
  if (p < Pn){
    size_t bp = (size_t)b*Pn + p;
    int info = objinfo[bp];
    int obj = info & 0xFF;
    bool ignored = (info & 256) != 0;
    int label = labels[b*On + obj];
    if (ov_prior[bp] < THRESHOLD_F) label = 0;
    bool pos = label > 0;
    const float* sc = odm_scores + bp*(size_t)Cn;
    float m = sc[0];
    #pragma unroll
    for (int c=1;c<Cn;c++) m = fmaxf(m, sc[c]);
    float se = 0.0f;
    #pragma unroll
    for (int c=0;c<Cn;c++) se += expf(sc[c]-m);
    float conf = logf(se) - (sc[label]-m);
    conf_neg[bp] = (pos || ignored) ? 0.0f : conf;
    if (pos){
      posv = 1; confpv = conf;
      float4 pc = ((const float4*)priors)[p];
      const float* g = odm_locs + bp*4;
      float cx = g[0]*pc.z/10.0f + pc.x;
      float cy = g[1]*pc.w/10.0f + pc.y;
      float w  = expf(g[2]/5.0f)*pc.z;
      float h  = expf(g[3]/5.0f)*pc.w;
      float dx1 = cx - w/2.0f, dy1 = cy - h/2.0f;
      float dx2 = cx + w/2.0f, dy2 = cy + h/2.0f;
      const float* gt = boxes + ((size_t)b*On + obj)*4;
      float gx1=gt[0], gy1=gt[1], gx2=gt[2], gy2=gt[3];
      float ltx=fmaxf(dx1,gx1), lty=fmaxf(dy1,gy1);
      float rbx=fminf(dx2,gx2), rby=fminf(dy2,gy2);
      float iw=fmaxf(rbx-ltx,0.0f), ih=fmaxf(rby-lty,0.0f);
      float inter=iw*ih;
      float ap=(dx2-dx1)*(dy2-dy1);
      float ag=(gx2-gx1)*(gy2-gy1);
      float iou = inter/((ap+ag)-inter);
      float cpx=(dx1+dx2)/2.0f, cpy=(dy1+dy2)/2.0f;
      float cgx=(gx1+gx2)/2.0f, cgy=(gy1+gy2)/2.0f;
      float ddx=cpx-cgx, ddy=cpy-cgy;
      float inter_diag = ddx*ddx + ddy*ddy;
      float cltx=fminf(dx1,gx1), clty=fminf(dy1,gy1);
      float crbx=fmaxf(dx2,gx2), crby=fmaxf(dy2,gy2);
      float odx=crbx-cltx, ody=crby-clty;
      float outer_diag = odx*odx + ody*ody;
      float diou = fminf(fmaxf(iou - inter_diag/outer_diag, -1.0f), 1.0f);
      locv = 1.0f - diou;
    }
  }
  __shared__ float sl[256]; __shared__ float scf[256]; __shared__ int sp[256];
  int t = threadIdx.x;
  sl[t]=locv; scf[t]=confpv; sp[t]=posv;
  __syncthreads();
  for (int st=128; st>0; st>>=1){
    if (t<st){ sl[t]+=sl[t+st]; scf[t]+=scf[t+st]; sp[t]+=sp[t+st]; }
    __syncthreads();
  }
  if (t==0){
    if (sl[0]  != 0.0f) atomicAdd(&acc[1], (double)sl[0]);
    if (scf[0] != 0.0f) atomicAdd(&acc[2], (double)scf[0]);
    if (sp[0]  != 0)    atomicAdd(&n_pos[b], sp[0]);
  }
}

// ---- phase E: per-batch sum of top-K of conf_neg via radix-select on float bits ----
__global__ void phaseE_kernel(const float* __restrict__ conf_neg,
                              const int* __restrict__ n_pos,
                              double* __restrict__ acc){
  int b = blockIdx.x, t = threadIdx.x;
  int K = 2 * n_pos[b];
  if (K <= 0) return;
  const float* cn = conf_neg + (size_t)b*Pn;
  if (K >= Pn){
    float s = 0.0f;
    for (int p=t; p<Pn; p+=256) s += cn[p];
    __shared__ float sr[256];
    sr[t]=s; __syncthreads();
    for (int st=128; st>0; st>>=1){ if (t<st) sr[t]+=sr[t+st]; __syncthreads(); }
    if (t==0) atomicAdd(&acc[3], (double)sr[0]);
    return;
  }
  __shared__ unsigned cnt[256];
  __shared__ float    sm[256];
  __shared__ int      s_krem;
  __shared__ unsigned s_prefix;
  __shared__ double   s_top;
  if (t==0){ s_krem = K; s_prefix = 0u; s_top = 0.0; }
  for (int shift=24; shift>=0; shift-=8){
    cnt[t]=0u; sm[t]=0.0f;
    __syncthreads();
    unsigned hm = (shift==24) ? 0u : (0xFFFFFFFFu << (shift+8));
    unsigned pref = s_prefix;
    for (int p=t; p<Pn; p+=256){
      float v = cn[p];
      unsigned bits = __float_as_uint(v);   // all values >= 0 -> uint order == float order
      if ((bits & hm) == pref){
        unsigned d = (bits >> shift) & 255u;
        atomicAdd(&cnt[d], 1u);
        atomicAdd(&sm[d], v);
      }
    }
    __syncthreads();
    if (t==0){
      int krem = s_krem; unsigned sel = 0u;
      for (int d=255; d>=0; d--){
        if ((int)cnt[d] < krem){ krem -= (int)cnt[d]; s_top += (double)sm[d]; }
        else { sel = (unsigned)d; break; }
      }
      s_prefix |= sel << shift;
      s_krem = krem;
    }
    __syncthreads();
  }
  if (t==0){
    float tval = __uint_as_float(s_prefix);   // the K-th largest value
    atomicAdd(&acc[3], s_top + (double)s_krem * (double)tval);
  }
}

// ---- final combine ----
__global__ void final_kernel(const int* __restrict__ n_pos,
                             const double* __restrict__ acc,
                             float* __restrict__ out){
  if (threadIdx.x==0 && blockIdx.x==0){
    int tp = 0;
    for (int b=0;b<Bn;b++) tp += n_pos[b];
    float total = (float)tp;
    float conf_loss = (float)(acc[3] + acc[2]) / total;
    float loc_loss  = (float)acc[1] / total;
    float seg_loss  = -(float)acc[0];
    out[0] = conf_loss + loc_loss + seg_loss;
  }
}

extern "C" void kernel_launch(void* const* d_in, const int* in_sizes, int n_in,
                              void* d_out, int out_size, void* d_ws, size_t ws_size,
                              hipStream_t stream) {
  const float* odm_locs   = (const float*)d_in[0];
  const float* odm_scores = (const float*)d_in[1];
  const float* att        = (const float*)d_in[2];
  const float* boxes      = (const float*)d_in[3];
  const int*   labels     = (const int*)d_in[4];
  const float* ign        = (const float*)d_in[5];
  const float* priors     = (const float*)d_in[6];
  float* out = (float*)d_out;

  size_t np = (size_t)Bn * Pn;
  float* ov_prior  = (float*)d_ws;                 // B*P f32
  int*   objinfo   = (int*)(ov_prior + np);        // B*P i32 (bits0-7 obj, bit8 ignored)
  float* conf_neg  = (float*)(objinfo + np);       // B*P f32
  float* ov_obj    = conf_neg + np;                // B*O f32
  int*   prior_obj = (int*)(ov_obj + (size_t)Bn*On); // B*O i32
  int*   n_pos     = prior_obj + (size_t)Bn*On;    // B i32
  double* acc      = (double*)(n_pos + Bn);        // [seg, loc, conf_pos, conf_hard]

  // zero only the accumulators (all big arrays are fully rewritten each call)
  hipMemsetAsync(n_pos, 0, Bn*sizeof(int) + 4*sizeof(double), stream);

  int pblocks = (Pn + 255) / 256;
  seg_kernel  <<<(ATT_N+255)/256, 256, 0, stream>>>(att, acc);
  phaseA_kernel<<<dim3(pblocks, Bn), 256, 0, stream>>>(boxes, ign, priors, ov_prior, objinfo);
  phaseB_kernel<<<dim3(On, Bn),      256, 0, stream>>>(boxes, priors, ov_obj, prior_obj);
  phaseC_kernel<<<1, 64, 0, stream>>>(ov_obj, prior_obj, ov_prior, objinfo);
  phaseD_kernel<<<dim3(pblocks, Bn), 256, 0, stream>>>(odm_locs, odm_scores, boxes, labels,
                                                       priors, ov_prior, objinfo,
                                                       conf_neg, n_pos, acc);
  phaseE_kernel<<<Bn, 256, 0, stream>>>(conf_neg, n_pos, acc);
  final_kernel<<<1, 64, 0, stream>>>(n_pos, acc, out);
}

// Round 7
// 380.386 us; speedup vs baseline: 1.4416x; 1.4416x over previous
//
#include <hip/hip_runtime.h>
#include <math.h>

#define Bn 32
#define Pn 42840
#define On 64
#define NIn 8
#define Cn 11
#define ATT_N (32*56*96)
#define THRESHOLD_F 0.4f
#define THETA_F 0.1f
#define CHn 16
#define CHUNK ((Pn + CHn - 1)/CHn)

// IoU of two corner-format boxes, mirroring the jnp op order exactly.
__device__ __forceinline__ float iou_c(float ax1,float ay1,float ax2,float ay2,
                                       float bx1,float by1,float bx2,float by2){
  float ltx=fmaxf(ax1,bx1), lty=fmaxf(ay1,by1);
  float rbx=fminf(ax2,bx2), rby=fminf(ay2,by2);
  float w=fmaxf(rbx-ltx,0.0f), h=fmaxf(rby-lty,0.0f);
  float inter=w*h;
  float aa=(ax2-ax1)*(ay2-ay1);
  float ab=(bx2-bx1)*(by2-by1);
  return inter/((aa+ab)-inter);
}

// ---- seg loss: sum of max(log1p(-a), -100); negated at the end ----
__global__ void seg_kernel(const float* __restrict__ att, double* __restrict__ acc){
  int i = blockIdx.x*256 + threadIdx.x;
  float v = 0.0f;
  if (i < ATT_N) v = fmaxf(log1pf(-att[i]), -100.0f);
  __shared__ float s[256];
  int t = threadIdx.x;
  s[t]=v; __syncthreads();
  for (int st=128; st>0; st>>=1){ if (t<st) s[t]+=s[t+st]; __syncthreads(); }
  if (t==0) atomicAdd(&acc[0], (double)s[0]);
}

// ---- phase A: per (b,p): max/argmax over objects (first occurrence), ignored flag ----
__global__ void phaseA_kernel(const float* __restrict__ boxes,
                              const float* __restrict__ ign,
                              const float* __restrict__ priors,
                              float* __restrict__ ov_prior,
                              int* __restrict__ objinfo){
  __shared__ float sb[On*4];
  __shared__ float si[NIn*4];
  int b = blockIdx.y;
  int t = threadIdx.x;
  if (t < On*4)  sb[t] = boxes[(size_t)b*On*4 + t];
  if (t < NIn*4) si[t] = ign[(size_t)b*NIn*4 + t];
  __syncthreads();
  int p = blockIdx.x*256 + t;
  if (p >= Pn) return;
  float4 pc = ((const float4*)priors)[p];
  float px1 = pc.x - pc.z/2.0f, py1 = pc.y - pc.w/2.0f;
  float px2 = pc.x + pc.z/2.0f, py2 = pc.y + pc.w/2.0f;
  float best = -1.0f; int besto = 0;
  #pragma unroll 4
  for (int o=0;o<On;o++){
    float v = iou_c(sb[4*o],sb[4*o+1],sb[4*o+2],sb[4*o+3], px1,py1,px2,py2);
    if (v > best){ best = v; besto = o; }   // strict > keeps first argmax
  }
  float ig = iou_c(si[0],si[1],si[2],si[3], px1,py1,px2,py2);
  #pragma unroll
  for (int o=1;o<NIn;o++)
    ig = fmaxf(ig, iou_c(si[4*o],si[4*o+1],si[4*o+2],si[4*o+3], px1,py1,px2,py2));
  size_t bp = (size_t)b*Pn + p;
  ov_prior[bp] = best;
  objinfo[bp]  = besto | ((ig >= THETA_F) ? 256 : 0);
}

// ---- phase B: per (b,o): max/argmax over P (first occurrence via packed key) ----
__global__ void phaseB_kernel(const float* __restrict__ boxes,
                              const float* __restrict__ priors,
                              float* __restrict__ ov_obj,
                              int* __restrict__ prior_obj){
  int b = blockIdx.y, o = blockIdx.x, t = threadIdx.x;
  const float* bx = boxes + ((size_t)b*On + o)*4;
  float ax1=bx[0], ay1=bx[1], ax2=bx[2], ay2=bx[3];
  unsigned long long key = 0ull;   // loses to any real key (low32=~p > 0)
  for (int p=t; p<Pn; p+=256){
    float4 pc = ((const float4*)priors)[p];
    float px1 = pc.x - pc.z/2.0f, py1 = pc.y - pc.w/2.0f;
    float px2 = pc.x + pc.z/2.0f, py2 = pc.y + pc.w/2.0f;
    float v = iou_c(ax1,ay1,ax2,ay2, px1,py1,px2,py2);  // v >= 0 -> bits ordered
    unsigned long long k = ((unsigned long long)__float_as_uint(v) << 32)
                         | (unsigned long long)(0xFFFFFFFFu - (unsigned)p);
    if (k > key) key = k;
  }
  __shared__ unsigned long long sk[256];
  sk[t] = key; __syncthreads();
  for (int st=128; st>0; st>>=1){
    if (t<st && sk[t+st] > sk[t]) sk[t] = sk[t+st];
    __syncthreads();
  }
  if (t==0){
    ov_obj[(size_t)b*On+o]   = __uint_as_float((unsigned)(sk[0] >> 32));
    prior_obj[(size_t)b*On+o]= (int)(0xFFFFFFFFu - (unsigned)(sk[0] & 0xFFFFFFFFu));
  }
}

// ---- phase C: sequential per-batch scatter (set 1.0; last-write-wins rank) ----
__global__ void phaseC_kernel(const float* __restrict__ ov_obj,
                              const int* __restrict__ prior_obj,
                              float* __restrict__ ov_prior,
                              int* __restrict__ objinfo){
  int b = threadIdx.x;
  if (b >= Bn) return;
  int rank = -1;
  for (int o=0;o<On;o++){
    if (ov_obj[(size_t)b*On+o] > 0.0f){
      rank++;                                   // jranks = cumsum(valid)-1
      int p = prior_obj[(size_t)b*On+o];
      size_t bp = (size_t)b*Pn + p;
      ov_prior[bp] = 1.0f;
      objinfo[bp] = (objinfo[bp] & 256) | rank; // ascending o => overwrite == max(jr)
    }
  }
}

// ---- phase D: labels, CE, DIoU over positives, conf_neg array, partial sums ----
__global__ void phaseD_kernel(const float* __restrict__ odm_locs,
                              const float* __restrict__ odm_scores,
                              const float* __restrict__ boxes,
                              const int* __restrict__ labels,
                              const float* __restrict__ priors,
                              const float* __restrict__ ov_prior,
                              const int* __restrict__ objinfo,
                              float* __restrict__ conf_neg,
                              int* __restrict__ n_pos,
                              double* __restrict__ acc){
  int b = blockIdx.y;
  int p = blockIdx.x*256 + threadIdx.x;
  float locv = 0.0f, confpv = 0.0f; int posv = 0;
  if (p < Pn){
    size_t bp = (size_t)b*Pn + p;
    int info = objinfo[bp];
    int obj = info & 0xFF;
    bool ignored = (info & 256) != 0;
    int label = labels[b*On + obj];
    if (ov_prior[bp] < THRESHOLD_F) label = 0;
    bool pos = label > 0;
    const float* sc = odm_scores + bp*(size_t)Cn;
    float m = sc[0];
    #pragma unroll
    for (int c=1;c<Cn;c++) m = fmaxf(m, sc[c]);
    float se = 0.0f;
    #pragma unroll
    for (int c=0;c<Cn;c++) se += expf(sc[c]-m);
    float conf = logf(se) - (sc[label]-m);
    conf_neg[bp] = (pos || ignored) ? 0.0f : conf;
    if (pos){
      posv = 1; confpv = conf;
      float4 pc = ((const float4*)priors)[p];
      const float* g = odm_locs + bp*4;
      float cx = g[0]*pc.z/10.0f + pc.x;
      float cy = g[1]*pc.w/10.0f + pc.y;
      float w  = expf(g[2]/5.0f)*pc.z;
      float h  = expf(g[3]/5.0f)*pc.w;
      float dx1 = cx - w/2.0f, dy1 = cy - h/2.0f;
      float dx2 = cx + w/2.0f, dy2 = cy + h/2.0f;
      const float* gt = boxes + ((size_t)b*On + obj)*4;
      float gx1=gt[0], gy1=gt[1], gx2=gt[2], gy2=gt[3];
      float ltx=fmaxf(dx1,gx1), lty=fmaxf(dy1,gy1);
      float rbx=fminf(dx2,gx2), rby=fminf(dy2,gy2);
      float iw=fmaxf(rbx-ltx,0.0f), ih=fmaxf(rby-lty,0.0f);
      float inter=iw*ih;
      float ap=(dx2-dx1)*(dy2-dy1);
      float ag=(gx2-gx1)*(gy2-gy1);
      float iou = inter/((ap+ag)-inter);
      float cpx=(dx1+dx2)/2.0f, cpy=(dy1+dy2)/2.0f;
      float cgx=(gx1+gx2)/2.0f, cgy=(gy1+gy2)/2.0f;
      float ddx=cpx-cgx, ddy=cpy-cgy;
      float inter_diag = ddx*ddx + ddy*ddy;
      float cltx=fminf(dx1,gx1), clty=fminf(dy1,gy1);
      float crbx=fmaxf(dx2,gx2), crby=fmaxf(dy2,gy2);
      float odx=crbx-cltx, ody=crby-clty;
      float outer_diag = odx*odx + ody*ody;
      float diou = fminf(fmaxf(iou - inter_diag/outer_diag, -1.0f), 1.0f);
      locv = 1.0f - diou;
    }
  }
  __shared__ float sl[256]; __shared__ float scf[256]; __shared__ int sp[256];
  int t = threadIdx.x;
  sl[t]=locv; scf[t]=confpv; sp[t]=posv;
  __syncthreads();
  for (int st=128; st>0; st>>=1){
    if (t<st){ sl[t]+=sl[t+st]; scf[t]+=scf[t+st]; sp[t]+=sp[t+st]; }
    __syncthreads();
  }
  if (t==0){
    if (sl[0]  != 0.0f) atomicAdd(&acc[1], (double)sl[0]);
    if (scf[0] != 0.0f) atomicAdd(&acc[2], (double)scf[0]);
    if (sp[0]  != 0)    atomicAdd(&n_pos[b], sp[0]);
  }
}

// ---- phase E (parallel radix-select, 3 rounds of 12/12/8 bits) ----
// Round r histogram: per-batch global histogram of the r-th digit, restricted
// to keys matching the prefix found so far. All values >= 0 so uint order of
// float bits == float order.
template<int ROUND>
__global__ void histE_kernel(const float* __restrict__ conf_neg,
                             const int* __restrict__ n_pos,
                             const unsigned* __restrict__ prefix,
                             unsigned* __restrict__ hist){
  int b = blockIdx.y, c = blockIdx.x, t = threadIdx.x;
  if (n_pos[b] <= 0) return;
  const int nb = (ROUND==2)?256:4096;
  __shared__ unsigned h[4096];
  for (int i=t;i<nb;i+=256) h[i]=0u;
  __syncthreads();
  unsigned pref = (ROUND==0)?0u:prefix[b];
  const float* cn = conf_neg + (size_t)b*Pn;
  int p0 = c*CHUNK, p1 = min(Pn, p0+CHUNK);
  for (int p=p0+t; p<p1; p+=256){
    unsigned key = __float_as_uint(cn[p]);
    if (ROUND==0){
      atomicAdd(&h[key>>20],1u);
    } else if (ROUND==1){
      if ((key>>20)==(pref>>20)) atomicAdd(&h[(key>>8)&0xFFFu],1u);
    } else {
      if ((key>>8)==(pref>>8)) atomicAdd(&h[key&0xFFu],1u);
    }
  }
  __syncthreads();
  unsigned* gh = hist + (size_t)b*4096;
  for (int i=t;i<nb;i+=256) if (h[i]) atomicAdd(&gh[i], h[i]);
}

// Pick the digit: largest bin index sel s.t. count(keys with digit > sel) < krem
// <= count(digit >= sel); new krem = krem - count(digit > sel).
template<int ROUND>
__global__ void scanE_kernel(const unsigned* __restrict__ hist,
                             const int* __restrict__ n_pos,
                             unsigned* __restrict__ prefix,
                             int* __restrict__ krem_st){
  int b = blockIdx.x, t = threadIdx.x;
  int K = 2*n_pos[b];
  if (K <= 0) return;
  const int nb = (ROUND==2)?256:4096;
  const int per = nb/256;
  const unsigned* gh = hist + (size_t)b*4096;
  unsigned cnt[per>0?per:1];
  unsigned ts = 0;
  #pragma unroll
  for (int i=0;i<per;i++){ cnt[i]=gh[t*per+i]; ts+=cnt[i]; }
  __shared__ unsigned sh[256];
  sh[t]=ts;
  __syncthreads();
  for (int off=1; off<256; off<<=1){
    unsigned v = (t+off<256)? sh[t+off]:0u;   // read (after barrier)
    __syncthreads();
    sh[t]+=v;                                  // write
    __syncthreads();
  }
  int krem = (ROUND==0)? K : krem_st[b];
  unsigned incl = sh[t];           // count of keys in bins >= this thread's lowest
  unsigned above = incl - ts;      // count in strictly-higher threads' bins
  if ((int)above < krem && krem <= (int)incl){
    int acc = (int)above;
    #pragma unroll
    for (int i=per-1;i>=0;i--){
      acc += (int)cnt[i];
      if (acc >= krem){
        unsigned sel = (unsigned)(t*per+i);
        int krem_new = krem - (acc - (int)cnt[i]);
        if (ROUND==0)      prefix[b]  = sel<<20;
        else if (ROUND==1) prefix[b] |= sel<<8;
        else               prefix[b] |= sel;
        krem_st[b]=krem_new;
        break;
      }
    }
  }
}

// Final: sum = sum(v > t) + krem * t  (exact "first K of descending sort")
__global__ void finalE_kernel(const float* __restrict__ conf_neg,
                              const int* __restrict__ n_pos,
                              const unsigned* __restrict__ prefix,
                              const int* __restrict__ krem_st,
                              double* __restrict__ acc){
  int b = blockIdx.y, c = blockIdx.x, t = threadIdx.x;
  int K = 2*n_pos[b];
  if (K <= 0) return;
  const float* cn = conf_neg + (size_t)b*Pn;
  int p0=c*CHUNK, p1=min(Pn,p0+CHUNK);
  float s=0.0f;
  if (K >= Pn){
    for (int p=p0+t;p<p1;p+=256) s += cn[p];
  } else {
    unsigned tb = prefix[b];
    for (int p=p0+t;p<p1;p+=256){
      float v = cn[p];
      if (__float_as_uint(v) > tb) s += v;
    }
  }
  __shared__ float sr[256];
  sr[t]=s; __syncthreads();
  for (int st=128;st>0;st>>=1){ if(t<st) sr[t]+=sr[t+st]; __syncthreads(); }
  if (t==0){
    double add = (double)sr[0];
    if (c==0 && K < Pn) add += (double)krem_st[b] * (double)__uint_as_float(prefix[b]);
    if (add != 0.0) atomicAdd(&acc[3], add);
  }
}

// ---- final combine ----
__global__ void final_kernel(const int* __restrict__ n_pos,
                             const double* __restrict__ acc,
                             float* __restrict__ out){
  if (threadIdx.x==0 && blockIdx.x==0){
    int tp = 0;
    for (int b=0;b<Bn;b++) tp += n_pos[b];
    float total = (float)tp;
    float conf_loss = (float)(acc[3] + acc[2]) / total;
    float loc_loss  = (float)acc[1] / total;
    float seg_loss  = -(float)acc[0];
    out[0] = conf_loss + loc_loss + seg_loss;
  }
}

extern "C" void kernel_launch(void* const* d_in, const int* in_sizes, int n_in,
                              void* d_out, int out_size, void* d_ws, size_t ws_size,
                              hipStream_t stream) {
  const float* odm_locs   = (const float*)d_in[0];
  const float* odm_scores = (const float*)d_in[1];
  const float* att        = (const float*)d_in[2];
  const float* boxes      = (const float*)d_in[3];
  const int*   labels     = (const int*)d_in[4];
  const float* ign        = (const float*)d_in[5];
  const float* priors     = (const float*)d_in[6];
  float* out = (float*)d_out;

  size_t np = (size_t)Bn * Pn;
  float* ov_prior  = (float*)d_ws;                 // B*P f32
  int*   objinfo   = (int*)(ov_prior + np);        // B*P i32 (bits0-7 obj, bit8 ignored)
  float* conf_neg  = (float*)(objinfo + np);       // B*P f32
  float* ov_obj    = conf_neg + np;                // B*O f32
  int*   prior_obj = (int*)(ov_obj + (size_t)Bn*On); // B*O i32
  int*   n_pos     = prior_obj + (size_t)Bn*On;    // B i32
  double* acc      = (double*)(n_pos + Bn);        // [seg, loc, conf_pos, conf_hard]

  // radix-select scratch lives in the ov_prior region (dead after phaseD):
  // 3 x Bn x 4096 u32 hists + Bn prefix + Bn krem  (1.5 MB < 5.4 MB)
  unsigned* histB  = (unsigned*)ov_prior;
  unsigned* prefix = histB + 3*(size_t)Bn*4096;
  int*      krem   = (int*)(prefix + Bn);

  // zero only the accumulators (all big arrays are fully rewritten each call)
  hipMemsetAsync(n_pos, 0, Bn*sizeof(int) + 4*sizeof(double), stream);

  int pblocks = (Pn + 255) / 256;
  seg_kernel  <<<(ATT_N+255)/256, 256, 0, stream>>>(att, acc);
  phaseA_kernel<<<dim3(pblocks, Bn), 256, 0, stream>>>(boxes, ign, priors, ov_prior, objinfo);
  phaseB_kernel<<<dim3(On, Bn),      256, 0, stream>>>(boxes, priors, ov_obj, prior_obj);
  phaseC_kernel<<<1, 64, 0, stream>>>(ov_obj, prior_obj, ov_prior, objinfo);
  phaseD_kernel<<<dim3(pblocks, Bn), 256, 0, stream>>>(odm_locs, odm_scores, boxes, labels,
                                                       priors, ov_prior, objinfo,
                                                       conf_neg, n_pos, acc);
  // ov_prior is dead from here; reuse as radix scratch.
  hipMemsetAsync(histB, 0, 3*(size_t)Bn*4096*sizeof(unsigned), stream);
  histE_kernel<0><<<dim3(CHn, Bn), 256, 0, stream>>>(conf_neg, n_pos, prefix, histB);
  scanE_kernel<0><<<Bn, 256, 0, stream>>>(histB, n_pos, prefix, krem);
  histE_kernel<1><<<dim3(CHn, Bn), 256, 0, stream>>>(conf_neg, n_pos, prefix, histB + (size_t)Bn*4096);
  scanE_kernel<1><<<Bn, 256, 0, stream>>>(histB + (size_t)Bn*4096, n_pos, prefix, krem);
  histE_kernel<2><<<dim3(CHn, Bn), 256, 0, stream>>>(conf_neg, n_pos, prefix, histB + 2*(size_t)Bn*4096);
  scanE_kernel<2><<<Bn, 256, 0, stream>>>(histB + 2*(size_t)Bn*4096, n_pos, prefix, krem);
  finalE_kernel<<<dim3(CHn, Bn), 256, 0, stream>>>(conf_neg, n_pos, prefix, krem, acc);
  final_kernel<<<1, 64, 0, stream>>>(n_pos, acc, out);
}